// Round 1
// baseline (74.841 us; speedup 1.0000x reference)
//
#include <hip/hip_runtime.h>

typedef __attribute__((ext_vector_type(8))) short short8;
typedef __attribute__((ext_vector_type(4))) float f32x4;

namespace {

__device__ __forceinline__ unsigned short f2bf(float f) {
    unsigned int u = __float_as_uint(f);
    u += 0x7fffu + ((u >> 16) & 1u);     // RNE to bf16
    return (unsigned short)(u >> 16);
}

// ---------------------------------------------------------------------------
// Unchanged (verified): lane-major fragment-coalesced taps. uint4 slot =
// (ic*8 + ot*2 + kt)*64 + lane, lane = g*16 + n. 8 bf16 taps (q flipped,
// q==7 zero) of tap-row a = 4kt+g (flipped, a==7 zero) for oc = 16*ot+n.
// ---------------------------------------------------------------------------
__global__ void prep_B(const float* __restrict__ ker, uint4* __restrict__ B2) {
    int t  = blockIdx.x * 256 + threadIdx.x;   // 16384 threads
    int a  = t & 7;
    int oc = (t >> 3) & 63;
    int ic = t >> 9;
    unsigned int d[4] = {0u, 0u, 0u, 0u};
    if (a < 7) {
        const float* row = ker + ((oc * 32 + ic) * 49) + (6 - a) * 7;
        float v[8];
#pragma unroll
        for (int q = 0; q < 7; ++q) v[q] = row[6 - q];
        v[7] = 0.0f;
#pragma unroll
        for (int j = 0; j < 4; ++j)
            d[j] = (unsigned int)f2bf(v[2 * j]) | ((unsigned int)f2bf(v[2 * j + 1]) << 16);
    }
    int ot = oc >> 4, nn = oc & 15, kt = a >> 2, gg = a & 3;
    B2[(ic * 8 + ot * 2 + kt) * 64 + gg * 16 + nn] = make_uint4(d[0], d[1], d[2], d[3]);
}

// ---------------------------------------------------------------------------
// x-split conv: grid 512 = b(8) x yp(32) x xh(2); block = 512 thr (8 waves).
// Block computes 2 output rows x 32 x (one xh half) x 64 oc over all 32 ic.
// Wave w = icg owns ic = 4w..4w+3: stages ITS OWN 4 planes into H (pair-
// packed 39-col window, pitch 40 dw, slot s = local col window start; slot s
// holds global cols (32xh+s-2, 32xh+s-3+1) as bf16x2) -- stage->compute is
// wave-local: NO barrier. r==8 plane overrun exists only for g==3/kt==1
// (tap row a==7, all-zero taps) -> clamp row to 7 (finite data x 0 = 0).
// LDS = 40 KB H + 32 KB P = 72 KB -> 2 blocks/CU overlap each other's
// barriers. Merge: 4 phases (one per nt); ALL 8 waves publish acc[nt] (b64-
// contiguous), barrier, ALL waves reduce 8-way + store (4x64B segments),
// barrier. No shrinking-participation tail.
// ---------------------------------------------------------------------------
__global__ __launch_bounds__(512, 4) void conv_mfma(
    const float* __restrict__ img,          // [8][32][64][64]
    const uint4* __restrict__ B2,           // prepped taps
    float* __restrict__ out)                // [8][64][64][64]
{
    __shared__ unsigned int H[10240];       // 32 planes x 8 rows x 40 dw = 40960 B
    __shared__ float P[8192];               // 32768 B publish buffer

    const int bid  = blockIdx.x;            // b*64 + yp*2 + xh
    const int xh   = bid & 1;
    const int yp   = (bid >> 1) & 31;
    const int b    = bid >> 6;
    const int y0   = yp * 2;
    const int tid  = threadIdx.x;
    const int lane = tid & 63;
    const int w    = tid >> 6;              // 8 waves; compute role: icg = w
    const int n    = lane & 15;
    const int g    = lane >> 4;

    const float* base = img + (size_t)b * 32 * 4096;

    // ---- stage: wave w stages planes 4w..4w+3, rows (y0-2..y0+5); no barrier.
    // lane l supplies slot l: first col (32xh + l - 2) mod 64; second via shfl.
    const int colg = (32 * xh + lane - 2) & 63;
    float v[32];
#pragma unroll
    for (int j = 0; j < 32; ++j) {
        const int ic  = w * 4 + (j >> 3);
        const int row = (y0 - 2 + (j & 7)) & 63;
        v[j] = base[ic * 4096 + row * 64 + colg];
    }
#pragma unroll
    for (int j = 0; j < 32; ++j) {
        const int ic = w * 4 + (j >> 3);
        const int r  = j & 7;
        const unsigned int h  = f2bf(v[j]);
        const unsigned int hn = (unsigned int)__shfl((int)h, (lane + 1) & 63);
        if (lane < 38) H[ic * 320 + r * 40 + lane] = h | (hn << 16);
    }
    // no __syncthreads: this wave only reads planes it wrote itself

    // ---- compute: 4 ic x 4 n-tiles x 4 oc-tiles ----
    f32x4 acc[4][4];
#pragma unroll
    for (int nt = 0; nt < 4; ++nt)
#pragma unroll
        for (int ot = 0; ot < 4; ++ot) acc[nt][ot] = (f32x4){0.f, 0.f, 0.f, 0.f};

#pragma unroll 1
    for (int ici = 0; ici < 4; ++ici) {
        const int ic = w * 4 + ici;
        uint4 bf[8];                              // q = ot*2 + kt
#pragma unroll
        for (int q = 0; q < 8; ++q)
            bf[q] = B2[(ic * 8 + q) * 64 + lane];

#pragma unroll
        for (int nt = 0; nt < 4; ++nt) {          // ry = nt>>1, mt = nt&1
            const int ry = nt >> 1;
            const int s0 = 16 * (nt & 1) + n;     // slot = x_local -> cols x-2..x+5
            const int r0 = ry + g;                // tap row a = g (kt=0)
            int r1 = r0 + 4;                      // tap row a = g+4 (kt=1)
            if (r1 > 7) r1 = 7;                   // only g==3 (zero taps): any finite data
            const int d0 = ic * 320 + r0 * 40 + s0;
            const int d1 = ic * 320 + r1 * 40 + s0;
            uint4 i0 = make_uint4(H[d0], H[d0 + 2], H[d0 + 4], H[d0 + 6]);
            uint4 i1 = make_uint4(H[d1], H[d1 + 2], H[d1 + 4], H[d1 + 6]);
            short8 f0 = __builtin_bit_cast(short8, i0);
            short8 f1 = __builtin_bit_cast(short8, i1);
#pragma unroll
            for (int ot = 0; ot < 4; ++ot) {
                f32x4 d = (f32x4){0.f, 0.f, 0.f, 0.f};
                d = __builtin_amdgcn_mfma_f32_16x16x32_bf16(
                        __builtin_bit_cast(short8, bf[2 * ot]),     f0, d, 0, 0, 0);
                d = __builtin_amdgcn_mfma_f32_16x16x32_bf16(
                        __builtin_bit_cast(short8, bf[2 * ot + 1]), f1, d, 0, 0, 0);
#pragma unroll
                for (int i = 0; i < 4; ++i)
                    acc[nt][ot][i] += __builtin_fabsf(d[i]);
            }
        }
    }

    // ---- merge + store: 4 symmetric all-wave phases (one per nt) ----
    // publish layout: region ih (0: acc[0..1], 1: acc[2..3] at +4096),
    // idx = (icg*4 + ot)*128 + lane*2  -> b64-contiguous writes and reads.
    const int ot_r = w >> 1;                      // reducer role: (ot_r, ih)
    const int ih   = w & 1;
    float* o = out + (size_t)b * 64 * 4096;
#pragma unroll
    for (int nt = 0; nt < 4; ++nt) {
#pragma unroll
        for (int ot = 0; ot < 4; ++ot) {
            const int idx = (w * 4 + ot) * 128 + lane * 2;
            P[idx]            = acc[nt][ot][0];
            P[idx + 1]        = acc[nt][ot][1];
            P[4096 + idx]     = acc[nt][ot][2];
            P[4096 + idx + 1] = acc[nt][ot][3];
        }
        __syncthreads();
        {
            float s0 = 0.f, s1 = 0.f;
#pragma unroll
            for (int icg = 0; icg < 8; ++icg) {
                const int idx = ih * 4096 + (icg * 4 + ot_r) * 128 + lane * 2;
                s0 += P[idx];
                s1 += P[idx + 1];
            }
            const int y   = y0 + (nt >> 1);
            const int xg  = 32 * xh + 16 * (nt & 1) + n;
            const int oc0 = 16 * ot_r + 4 * g + 2 * ih;
            o[(size_t)oc0 * 4096 + y * 64 + xg]       = s0;
            o[(size_t)(oc0 + 1) * 4096 + y * 64 + xg] = s1;
        }
        __syncthreads();                          // P reused next phase
    }
}

} // namespace

extern "C" void kernel_launch(void* const* d_in, const int* in_sizes, int n_in,
                              void* d_out, int out_size, void* d_ws, size_t ws_size,
                              hipStream_t stream) {
    const float* img = (const float*)d_in[0];   // [8][32][64][64]
    const float* ker = (const float*)d_in[1];   // [64][32][7][7]
    float* out = (float*)d_out;                 // [8][64][64][64]
    uint4* B2 = (uint4*)d_ws;                   // 256 KB lane-major taps

    prep_B<<<dim3(64), dim3(256), 0, stream>>>(ker, B2);
    conv_mfma<<<dim3(512), dim3(512), 0, stream>>>(img, B2, out);
}